// Round 5
// baseline (389.254 us; speedup 1.0000x reference)
//
#include <hip/hip_runtime.h>

#define NN 1024
#define CH ((size_t)NN * (size_t)NN)
#define BAND 8

// ---- float4 elementwise helpers ----
__device__ __forceinline__ float4 v_add(float4 a, float4 b) {
    return make_float4(a.x + b.x, a.y + b.y, a.z + b.z, a.w + b.w);
}
__device__ __forceinline__ float4 v_sub(float4 a, float4 b) {
    return make_float4(a.x - b.x, a.y - b.y, a.z - b.z, a.w - b.w);
}
__device__ __forceinline__ float4 v_mul(float4 a, float4 b) {
    return make_float4(a.x * b.x, a.y * b.y, a.z * b.z, a.w * b.w);
}
__device__ __forceinline__ float4 v_fma(float4 a, float4 b, float4 c) {
    return make_float4(fmaf(a.x, b.x, c.x), fmaf(a.y, b.y, c.y),
                       fmaf(a.z, b.z, c.z), fmaf(a.w, b.w, c.w));
}
__device__ __forceinline__ float4 v_fmas(float s, float4 a, float4 c) {
    return make_float4(fmaf(s, a.x, c.x), fmaf(s, a.y, c.y),
                       fmaf(s, a.z, c.z), fmaf(s, a.w, c.w));
}
__device__ __forceinline__ float4 v_scale(float s, float4 a) {
    return make_float4(s * a.x, s * a.y, s * a.z, s * a.w);
}

__device__ __forceinline__ float4 ldf4(const float* p) { return *(const float4*)p; }

__device__ __forceinline__ int clampr(int r) { return r < 0 ? 0 : (r > NN - 1 ? NN - 1 : r); }

// x-derivatives for 4 px; halo scalars lz,lw (left f4 .z/.w) and rx,ry (right f4 .x/.y).
__device__ __forceinline__ void xder(float lz, float lw, float4 c, float rx, float ry,
                                     int tx, float4& d1, float4& d2) {
    d1.x = 0.5f * (c.y - lw);
    d1.y = 0.5f * (c.z - c.x);
    d1.z = 0.5f * (c.w - c.y);
    d1.w = 0.5f * (rx - c.z);
    d2.x = 0.25f * (c.z - 2.0f * c.x + lz);
    d2.y = 0.25f * (c.w - 2.0f * c.y + lw);
    d2.z = 0.25f * (rx - 2.0f * c.z + c.x);
    d2.w = 0.25f * (ry - 2.0f * c.w + c.y);
    if (tx == 0) {                  // pixels i=0, i=1
        d1.x = c.y - c.x;
        d2.x = 0.5f * c.z - c.y + 0.5f * c.x;
        d2.y = 0.25f * c.w - 0.75f * c.y + 0.5f * c.x;
    } else if (tx == NN / 4 - 1) {  // pixels i=n-2, i=n-1
        d2.z = 0.25f * c.x - 0.75f * c.z + 0.5f * c.w;
        d1.w = c.w - c.z;
        d2.w = 0.5f * c.y - c.z + 0.5f * c.w;
    }
}

__device__ __forceinline__ void xder1(float lw, float4 c, float rx, int tx, float4& d1) {
    d1.x = 0.5f * (c.y - lw);
    d1.y = 0.5f * (c.z - c.x);
    d1.z = 0.5f * (c.w - c.y);
    d1.w = 0.5f * (rx - c.z);
    if (tx == 0)               d1.x = c.y - c.x;
    else if (tx == NN / 4 - 1) d1.w = c.w - c.z;
}

// y-derivatives from ring rows y-2..y+2 (w0..w4). y is block-uniform.
__device__ __forceinline__ void yder(float4 w0, float4 w1, float4 w2, float4 w3, float4 w4,
                                     int y, float4& d1, float4& d2) {
    if (y == 0) {
        d1 = v_sub(w3, w2);
        d2 = v_fmas(0.5f, w4, v_fmas(0.5f, w2, v_scale(-1.0f, w3)));
    } else if (y == 1) {
        d1 = v_scale(0.5f, v_sub(w3, w1));
        d2 = v_fmas(0.25f, w4, v_fmas(-0.75f, w2, v_scale(0.5f, w1)));
    } else if (y == NN - 2) {
        d1 = v_scale(0.5f, v_sub(w3, w1));
        d2 = v_fmas(0.25f, w0, v_fmas(-0.75f, w2, v_scale(0.5f, w3)));
    } else if (y == NN - 1) {
        d1 = v_sub(w2, w1);
        d2 = v_fmas(0.5f, w0, v_fmas(0.5f, w2, v_scale(-1.0f, w1)));
    } else {
        d1 = v_scale(0.5f, v_sub(w3, w1));
        d2 = v_scale(0.25f, v_add(v_sub(w4, v_scale(2.0f, w2)), w0));
    }
}

__device__ __forceinline__ void yder1(float4 p0, float4 p1, float4 p2, int y, float4& d1) {
    if (y == 0)           d1 = v_sub(p2, p1);
    else if (y == NN - 1) d1 = v_sub(p1, p0);
    else                  d1 = v_scale(0.5f, v_sub(p2, p0));
}

// Block = 256 threads = one full row (256 float4); processes BAND=8 consecutive rows
// with a register ring (U/V/T 5-deep, P 3-deep) so each row advance loads only the
// 7 unique float4/thread. x-halo via __shfl (lane+-1); wave-boundary lanes patch via
// tiny masked global loads. XCD swizzle: XCD k owns a contiguous 128-row band/batch.
__global__ __launch_bounds__(256, 3) void physics_residual_kernel(
    const float* __restrict__ fnow, const float* __restrict__ fnext,
    double* __restrict__ part)
{
    const int tx   = threadIdx.x;
    const int lane = tx & 63;
    const int flat = blockIdx.x;
    // flat: bits0-2 = xcd, bits3-6 = band-within-xcd (16), bits7-9 = batch
    const int band = ((flat & 7) << 4) | ((flat >> 3) & 15);   // 0..127
    const int b    = flat >> 7;                                 // 0..7
    const int y0   = band * BAND;

    const size_t cb = (size_t)b * 4 * CH + (size_t)tx * 4;
    const float* Up  = fnext + cb;
    const float* Vp  = Up + CH;
    const float* Tp  = Vp + CH;
    const float* Pp  = Tp + CH;
    const float* Unp = fnow + cb;
    const float* Vnp = Unp + CH;
    const float* Tnp = Vnp + CH;

    const bool eL = (lane == 0)  && (tx != 0);
    const bool eR = (lane == 63) && (tx != NN / 4 - 1);

    // ---- init rings: rows y0-2..y0+2 (clamped low; y0+2 <= 1018 always valid) ----
    float4 U0 = ldf4(Up + (size_t)clampr(y0 - 2) * NN);
    float4 U1 = ldf4(Up + (size_t)clampr(y0 - 1) * NN);
    float4 U2 = ldf4(Up + (size_t)y0 * NN);
    float4 U3 = ldf4(Up + (size_t)(y0 + 1) * NN);
    float4 U4 = ldf4(Up + (size_t)(y0 + 2) * NN);
    float4 V0 = ldf4(Vp + (size_t)clampr(y0 - 2) * NN);
    float4 V1 = ldf4(Vp + (size_t)clampr(y0 - 1) * NN);
    float4 V2 = ldf4(Vp + (size_t)y0 * NN);
    float4 V3 = ldf4(Vp + (size_t)(y0 + 1) * NN);
    float4 V4 = ldf4(Vp + (size_t)(y0 + 2) * NN);
    float4 T0 = ldf4(Tp + (size_t)clampr(y0 - 2) * NN);
    float4 T1 = ldf4(Tp + (size_t)clampr(y0 - 1) * NN);
    float4 T2 = ldf4(Tp + (size_t)y0 * NN);
    float4 T3 = ldf4(Tp + (size_t)(y0 + 1) * NN);
    float4 T4 = ldf4(Tp + (size_t)(y0 + 2) * NN);
    float4 P0 = ldf4(Pp + (size_t)clampr(y0 - 1) * NN);
    float4 P1 = ldf4(Pp + (size_t)y0 * NN);
    float4 P2 = ldf4(Pp + (size_t)(y0 + 1) * NN);

    float acc = 0.0f;

    #pragma unroll 2
    for (int k = 0; k < BAND; ++k) {
        const int y = y0 + k;
        const size_t yc = (size_t)y * NN;

        // ---- prefetch: 7 unique float4 / thread (next ring rows + now-fields) ----
        float4 nU  = ldf4(Up + (size_t)clampr(y + 3) * NN);
        float4 nV  = ldf4(Vp + (size_t)clampr(y + 3) * NN);
        float4 nT  = ldf4(Tp + (size_t)clampr(y + 3) * NN);
        float4 nP  = ldf4(Pp + (size_t)clampr(y + 2) * NN);
        float4 cUn = ldf4(Unp + yc);
        float4 cVn = ldf4(Vnp + yc);
        float4 cTn = ldf4(Tnp + yc);

        // ---- x-halo for center row: shuffle from lane+-1 ----
        float Ulz = __shfl_up(U2.z, 1), Ulw = __shfl_up(U2.w, 1);
        float Urx = __shfl_down(U2.x, 1), Ury = __shfl_down(U2.y, 1);
        float Vlz = __shfl_up(V2.z, 1), Vlw = __shfl_up(V2.w, 1);
        float Vrx = __shfl_down(V2.x, 1), Vry = __shfl_down(V2.y, 1);
        float Tlz = __shfl_up(T2.z, 1), Tlw = __shfl_up(T2.w, 1);
        float Trx = __shfl_down(T2.x, 1), Try = __shfl_down(T2.y, 1);
        float Plw = __shfl_up(P1.w, 1);
        float Prx = __shfl_down(P1.x, 1);

        // wave-boundary patch (1 active lane; L1/L2 hits; issued early, used late)
        if (eL) {
            float4 t;
            t = ldf4(Up + yc - 4); Ulz = t.z; Ulw = t.w;
            t = ldf4(Vp + yc - 4); Vlz = t.z; Vlw = t.w;
            t = ldf4(Tp + yc - 4); Tlz = t.z; Tlw = t.w;
            t = ldf4(Pp + yc - 4); Plw = t.w;
        }
        if (eR) {
            float4 t;
            t = ldf4(Up + yc + 4); Urx = t.x; Ury = t.y;
            t = ldf4(Vp + yc + 4); Vrx = t.x; Vry = t.y;
            t = ldf4(Tp + yc + 4); Trx = t.x; Try = t.y;
            t = ldf4(Pp + yc + 4); Prx = t.x;
        }

        // ---- y-derivatives (ring, no memory) ----
        float4 Udy, Udyy, Vdy, Vdyy, Tdy, Tdyy, Pdy;
        yder(U0, U1, U2, U3, U4, y, Udy, Udyy);
        yder(V0, V1, V2, V3, V4, y, Vdy, Vdyy);
        yder(T0, T1, T2, T3, T4, y, Tdy, Tdyy);
        yder1(P0, P1, P2, y, Pdy);

        // ---- x-derivatives ----
        float4 Udx, Udxx, Vdx, Vdxx, Tdx, Tdxx, Pdx;
        xder(Ulz, Ulw, U2, Urx, Ury, tx, Udx, Udxx);
        xder(Vlz, Vlw, V2, Vrx, Vry, tx, Vdx, Vdxx);
        xder(Tlz, Tlw, T2, Trx, Try, tx, Tdx, Tdxx);
        xder1(Plw, P1, Prx, tx, Pdx);

        // ---- residuals ----
        float4 cont = v_add(Udx, Vdy);

        float4 rx4 = v_fmas(100.0f, v_sub(U2, cUn), Pdx);
        rx4 = v_fma(U2, Udx, rx4);
        rx4 = v_fma(cVn, Udy, rx4);
        rx4 = v_fmas(-0.71f, v_add(Udxx, Udyy), rx4);
        rx4 = v_fmas(7.1f, U2, rx4);

        float4 ry4 = v_fmas(100.0f, v_sub(V2, cVn), Pdy);
        ry4 = v_fma(cUn, Vdx, ry4);
        ry4 = v_fma(V2, Vdy, ry4);
        ry4 = v_fmas(-0.71f, v_add(Vdxx, Vdyy), ry4);
        ry4 = v_fmas(-710.0f, T2, ry4);
        ry4 = v_fmas(78.1f, V2, ry4);

        float4 rt4 = v_scale(100.0f, v_sub(T2, cTn));
        rt4 = v_fma(cUn, Tdx, rt4);
        rt4 = v_fma(cVn, Tdy, rt4);
        rt4 = v_fmas(-1.6666666666666667f, v_add(Tdxx, Tdyy), rt4);
        rt4 = v_fmas(-0.1f, T2, rt4);

        float4 sq = v_mul(cont, cont);
        sq = v_fma(rx4, rx4, sq);
        sq = v_fma(ry4, ry4, sq);
        sq = v_fma(rt4, rt4, sq);
        acc += (sq.x + sq.y) + (sq.z + sq.w);

        // ---- shift rings ----
        U0 = U1; U1 = U2; U2 = U3; U3 = U4; U4 = nU;
        V0 = V1; V1 = V2; V2 = V3; V3 = V4; V4 = nV;
        T0 = T1; T1 = T2; T2 = T3; T3 = T4; T4 = nT;
        P0 = P1; P1 = P2; P2 = nP;
    }

    // ---- block reduction -> per-block double partial ----
    double d = (double)acc;
    #pragma unroll
    for (int off = 32; off; off >>= 1) d += __shfl_down(d, off, 64);

    __shared__ double lsum[4];
    const int wv = tx >> 6;
    if (lane == 0) lsum[wv] = d;
    __syncthreads();
    if (tx == 0) {
        part[flat] = lsum[0] + lsum[1] + lsum[2] + lsum[3];
    }
}

__global__ __launch_bounds__(1024) void final_reduce_kernel(
    const double* __restrict__ part, int n, float* __restrict__ out)
{
    double s = 0.0;
    for (int i = threadIdx.x; i < n; i += 1024) s += part[i];

    #pragma unroll
    for (int off = 32; off; off >>= 1) s += __shfl_down(s, off, 64);

    __shared__ double lsum[16];
    const int lane = threadIdx.x & 63;
    const int wv   = threadIdx.x >> 6;
    if (lane == 0) lsum[wv] = s;
    __syncthreads();
    if (threadIdx.x == 0) {
        double tot = 0.0;
        #pragma unroll
        for (int i = 0; i < 16; ++i) tot += lsum[i];
        tot *= (1e-4 / 8388608.0);   // BASE_SCALE / mean-count (same for all 4 terms)
        tot = fmin(fmax(tot, 1e-10), 1.0);
        out[0] = (float)tot;
    }
}

extern "C" void kernel_launch(void* const* d_in, const int* in_sizes, int n_in,
                              void* d_out, int out_size, void* d_ws, size_t ws_size,
                              hipStream_t stream) {
    const float* fnow  = (const float*)d_in[0];
    const float* fnext = (const float*)d_in[1];
    double* part = (double*)d_ws;          // 1024 doubles = 8 KiB scratch
    float*  out  = (float*)d_out;

    const int nblk = (NN / BAND) * 8;      // 1024 blocks
    physics_residual_kernel<<<dim3(nblk), 256, 0, stream>>>(fnow, fnext, part);
    final_reduce_kernel<<<1, 1024, 0, stream>>>(part, nblk, out);
}

// Round 6
// 271.931 us; speedup vs baseline: 1.4314x; 1.4314x over previous
//
#include <hip/hip_runtime.h>

#define NN 1024
#define CH ((size_t)NN * (size_t)NN)
#define BAND 8

// ---- float4 elementwise helpers ----
__device__ __forceinline__ float4 v_add(float4 a, float4 b) {
    return make_float4(a.x + b.x, a.y + b.y, a.z + b.z, a.w + b.w);
}
__device__ __forceinline__ float4 v_sub(float4 a, float4 b) {
    return make_float4(a.x - b.x, a.y - b.y, a.z - b.z, a.w - b.w);
}
__device__ __forceinline__ float4 v_mul(float4 a, float4 b) {
    return make_float4(a.x * b.x, a.y * b.y, a.z * b.z, a.w * b.w);
}
__device__ __forceinline__ float4 v_fma(float4 a, float4 b, float4 c) {
    return make_float4(fmaf(a.x, b.x, c.x), fmaf(a.y, b.y, c.y),
                       fmaf(a.z, b.z, c.z), fmaf(a.w, b.w, c.w));
}
__device__ __forceinline__ float4 v_fmas(float s, float4 a, float4 c) {
    return make_float4(fmaf(s, a.x, c.x), fmaf(s, a.y, c.y),
                       fmaf(s, a.z, c.z), fmaf(s, a.w, c.w));
}
__device__ __forceinline__ float4 v_scale(float s, float4 a) {
    return make_float4(s * a.x, s * a.y, s * a.z, s * a.w);
}

__device__ __forceinline__ float4 ldf4(const float* p) { return *(const float4*)p; }

__device__ __forceinline__ int clampr(int r) { return r < 0 ? 0 : (r > NN - 1 ? NN - 1 : r); }

// x-derivatives for 4 px; halo scalars lz,lw (left f4 .z/.w) and rx,ry (right f4 .x/.y).
__device__ __forceinline__ void xder(float lz, float lw, float4 c, float rx, float ry,
                                     int tx, float4& d1, float4& d2) {
    d1.x = 0.5f * (c.y - lw);
    d1.y = 0.5f * (c.z - c.x);
    d1.z = 0.5f * (c.w - c.y);
    d1.w = 0.5f * (rx - c.z);
    d2.x = 0.25f * (c.z - 2.0f * c.x + lz);
    d2.y = 0.25f * (c.w - 2.0f * c.y + lw);
    d2.z = 0.25f * (rx - 2.0f * c.z + c.x);
    d2.w = 0.25f * (ry - 2.0f * c.w + c.y);
    if (tx == 0) {                  // pixels i=0, i=1
        d1.x = c.y - c.x;
        d2.x = 0.5f * c.z - c.y + 0.5f * c.x;
        d2.y = 0.25f * c.w - 0.75f * c.y + 0.5f * c.x;
    } else if (tx == NN / 4 - 1) {  // pixels i=n-2, i=n-1
        d2.z = 0.25f * c.x - 0.75f * c.z + 0.5f * c.w;
        d1.w = c.w - c.z;
        d2.w = 0.5f * c.y - c.z + 0.5f * c.w;
    }
}

__device__ __forceinline__ void xder1(float lw, float4 c, float rx, int tx, float4& d1) {
    d1.x = 0.5f * (c.y - lw);
    d1.y = 0.5f * (c.z - c.x);
    d1.z = 0.5f * (c.w - c.y);
    d1.w = 0.5f * (rx - c.z);
    if (tx == 0)               d1.x = c.y - c.x;
    else if (tx == NN / 4 - 1) d1.w = c.w - c.z;
}

// y-derivatives from ring rows y-2..y+2 (w0..w4). y is block-uniform.
__device__ __forceinline__ void yder(float4 w0, float4 w1, float4 w2, float4 w3, float4 w4,
                                     int y, float4& d1, float4& d2) {
    if (y == 0) {
        d1 = v_sub(w3, w2);
        d2 = v_fmas(0.5f, w4, v_fmas(0.5f, w2, v_scale(-1.0f, w3)));
    } else if (y == 1) {
        d1 = v_scale(0.5f, v_sub(w3, w1));
        d2 = v_fmas(0.25f, w4, v_fmas(-0.75f, w2, v_scale(0.5f, w1)));
    } else if (y == NN - 2) {
        d1 = v_scale(0.5f, v_sub(w3, w1));
        d2 = v_fmas(0.25f, w0, v_fmas(-0.75f, w2, v_scale(0.5f, w3)));
    } else if (y == NN - 1) {
        d1 = v_sub(w2, w1);
        d2 = v_fmas(0.5f, w0, v_fmas(0.5f, w2, v_scale(-1.0f, w1)));
    } else {
        d1 = v_scale(0.5f, v_sub(w3, w1));
        d2 = v_scale(0.25f, v_add(v_sub(w4, v_scale(2.0f, w2)), w0));
    }
}

__device__ __forceinline__ void yder1(float4 p0, float4 p1, float4 p2, int y, float4& d1) {
    if (y == 0)           d1 = v_sub(p2, p1);
    else if (y == NN - 1) d1 = v_sub(p1, p0);
    else                  d1 = v_scale(0.5f, v_sub(p2, p0));
}

// Block = 256 threads = one full row of float4; BAND=8 rows per block via register
// ring (U/V/T 5-deep, P 3-deep). x-halo comes from LDS (center rows staged each
// iteration), NOT from extra global loads and NOT from shuffles (R5 spilled).
// Global requests: 7 float4/thread/row = near-unique minimum.
// XCD swizzle: XCD k owns a contiguous 128-row band per batch.
__global__ __launch_bounds__(256) void physics_residual_kernel(
    const float* __restrict__ fnow, const float* __restrict__ fnext,
    double* __restrict__ part)
{
    const int tx   = threadIdx.x;
    const int flat = blockIdx.x;
    // flat: bits0-2 = xcd, bits3-6 = band-within-xcd (16), bits7-9 = batch
    const int band = ((flat & 7) << 4) | ((flat >> 3) & 15);   // 0..127
    const int b    = flat >> 7;                                 // 0..7
    const int y0   = band * BAND;

    const size_t cb = (size_t)b * 4 * CH + (size_t)tx * 4;
    const float* Up  = fnext + cb;
    const float* Vp  = Up + CH;
    const float* Tp  = Vp + CH;
    const float* Pp  = Tp + CH;
    const float* Unp = fnow + cb;
    const float* Vnp = Unp + CH;
    const float* Tnp = Vnp + CH;

    // LDS staging for x-halo: slot [tx+1] is the center; [0]/[257] are pads so
    // edge threads read in-bounds (their halo values are ignored by edge formulas).
    __shared__ float4 hU[258], hV[258], hT[258], hP[258];

    // ---- init rings: rows y0-2..y0+2 (clamped low; y0+2 <= 1018 always valid) ----
    float4 U0 = ldf4(Up + (size_t)clampr(y0 - 2) * NN);
    float4 U1 = ldf4(Up + (size_t)clampr(y0 - 1) * NN);
    float4 U2 = ldf4(Up + (size_t)y0 * NN);
    float4 U3 = ldf4(Up + (size_t)(y0 + 1) * NN);
    float4 U4 = ldf4(Up + (size_t)(y0 + 2) * NN);
    float4 V0 = ldf4(Vp + (size_t)clampr(y0 - 2) * NN);
    float4 V1 = ldf4(Vp + (size_t)clampr(y0 - 1) * NN);
    float4 V2 = ldf4(Vp + (size_t)y0 * NN);
    float4 V3 = ldf4(Vp + (size_t)(y0 + 1) * NN);
    float4 V4 = ldf4(Vp + (size_t)(y0 + 2) * NN);
    float4 T0 = ldf4(Tp + (size_t)clampr(y0 - 2) * NN);
    float4 T1 = ldf4(Tp + (size_t)clampr(y0 - 1) * NN);
    float4 T2 = ldf4(Tp + (size_t)y0 * NN);
    float4 T3 = ldf4(Tp + (size_t)(y0 + 1) * NN);
    float4 T4 = ldf4(Tp + (size_t)(y0 + 2) * NN);
    float4 P0 = ldf4(Pp + (size_t)clampr(y0 - 1) * NN);
    float4 P1 = ldf4(Pp + (size_t)y0 * NN);
    float4 P2 = ldf4(Pp + (size_t)(y0 + 1) * NN);

    float acc = 0.0f;

    #pragma unroll 1
    for (int k = 0; k < BAND; ++k) {
        const int y = y0 + k;
        const size_t yc = (size_t)y * NN;

        // ---- the 7 unique global loads for this row (issued first, used last) ----
        float4 nU  = ldf4(Up + (size_t)clampr(y + 3) * NN);
        float4 nV  = ldf4(Vp + (size_t)clampr(y + 3) * NN);
        float4 nT  = ldf4(Tp + (size_t)clampr(y + 3) * NN);
        float4 nP  = ldf4(Pp + (size_t)clampr(y + 2) * NN);
        float4 cUn = ldf4(Unp + yc);
        float4 cVn = ldf4(Vnp + yc);
        float4 cTn = ldf4(Tnp + yc);

        // ---- stage center rows to LDS for x-halo ----
        __syncthreads();                  // previous iteration's reads complete
        hU[tx + 1] = U2;
        hV[tx + 1] = V2;
        hT[tx + 1] = T2;
        hP[tx + 1] = P1;
        if (tx == 0)   { hU[0]   = U2; hV[0]   = V2; hT[0]   = T2; hP[0]   = P1; }
        if (tx == 255) { hU[257] = U2; hV[257] = V2; hT[257] = T2; hP[257] = P1; }
        __syncthreads();

        // halo scalars: left f4's .z/.w and right f4's .x/.y
        const float* hUf = (const float*)hU;
        const float* hVf = (const float*)hV;
        const float* hTf = (const float*)hT;
        const float* hPf = (const float*)hP;
        const int ci = (tx + 1) * 4;
        float2 Ul = *(const float2*)&hUf[ci - 2];
        float2 Ur = *(const float2*)&hUf[ci + 4];
        float2 Vl = *(const float2*)&hVf[ci - 2];
        float2 Vr = *(const float2*)&hVf[ci + 4];
        float2 Tl = *(const float2*)&hTf[ci - 2];
        float2 Tr = *(const float2*)&hTf[ci + 4];
        float  Plw = hPf[ci - 1];
        float  Prx = hPf[ci + 4];

        // ---- y-derivatives (ring, no memory) ----
        float4 Udy, Udyy, Vdy, Vdyy, Tdy, Tdyy, Pdy;
        yder(U0, U1, U2, U3, U4, y, Udy, Udyy);
        yder(V0, V1, V2, V3, V4, y, Vdy, Vdyy);
        yder(T0, T1, T2, T3, T4, y, Tdy, Tdyy);
        yder1(P0, P1, P2, y, Pdy);

        // ---- x-derivatives ----
        float4 Udx, Udxx, Vdx, Vdxx, Tdx, Tdxx, Pdx;
        xder(Ul.x, Ul.y, U2, Ur.x, Ur.y, tx, Udx, Udxx);
        xder(Vl.x, Vl.y, V2, Vr.x, Vr.y, tx, Vdx, Vdxx);
        xder(Tl.x, Tl.y, T2, Tr.x, Tr.y, tx, Tdx, Tdxx);
        xder1(Plw, P1, Prx, tx, Pdx);

        // ---- residuals ----
        float4 cont = v_add(Udx, Vdy);

        float4 rx4 = v_fmas(100.0f, v_sub(U2, cUn), Pdx);
        rx4 = v_fma(U2, Udx, rx4);
        rx4 = v_fma(cVn, Udy, rx4);
        rx4 = v_fmas(-0.71f, v_add(Udxx, Udyy), rx4);
        rx4 = v_fmas(7.1f, U2, rx4);

        float4 ry4 = v_fmas(100.0f, v_sub(V2, cVn), Pdy);
        ry4 = v_fma(cUn, Vdx, ry4);
        ry4 = v_fma(V2, Vdy, ry4);
        ry4 = v_fmas(-0.71f, v_add(Vdxx, Vdyy), ry4);
        ry4 = v_fmas(-710.0f, T2, ry4);
        ry4 = v_fmas(78.1f, V2, ry4);

        float4 rt4 = v_scale(100.0f, v_sub(T2, cTn));
        rt4 = v_fma(cUn, Tdx, rt4);
        rt4 = v_fma(cVn, Tdy, rt4);
        rt4 = v_fmas(-1.6666666666666667f, v_add(Tdxx, Tdyy), rt4);
        rt4 = v_fmas(-0.1f, T2, rt4);

        float4 sq = v_mul(cont, cont);
        sq = v_fma(rx4, rx4, sq);
        sq = v_fma(ry4, ry4, sq);
        sq = v_fma(rt4, rt4, sq);
        acc += (sq.x + sq.y) + (sq.z + sq.w);

        // ---- shift rings ----
        U0 = U1; U1 = U2; U2 = U3; U3 = U4; U4 = nU;
        V0 = V1; V1 = V2; V2 = V3; V3 = V4; V4 = nV;
        T0 = T1; T1 = T2; T2 = T3; T3 = T4; T4 = nT;
        P0 = P1; P1 = P2; P2 = nP;
    }

    // ---- block reduction -> per-block double partial ----
    double d = (double)acc;
    #pragma unroll
    for (int off = 32; off; off >>= 1) d += __shfl_down(d, off, 64);

    __shared__ double lsum[4];
    const int lane = tx & 63;
    const int wv   = tx >> 6;
    if (lane == 0) lsum[wv] = d;
    __syncthreads();
    if (tx == 0) {
        part[flat] = lsum[0] + lsum[1] + lsum[2] + lsum[3];
    }
}

__global__ __launch_bounds__(1024) void final_reduce_kernel(
    const double* __restrict__ part, int n, float* __restrict__ out)
{
    double s = 0.0;
    for (int i = threadIdx.x; i < n; i += 1024) s += part[i];

    #pragma unroll
    for (int off = 32; off; off >>= 1) s += __shfl_down(s, off, 64);

    __shared__ double lsum[16];
    const int lane = threadIdx.x & 63;
    const int wv   = threadIdx.x >> 6;
    if (lane == 0) lsum[wv] = s;
    __syncthreads();
    if (threadIdx.x == 0) {
        double tot = 0.0;
        #pragma unroll
        for (int i = 0; i < 16; ++i) tot += lsum[i];
        tot *= (1e-4 / 8388608.0);   // BASE_SCALE / mean-count (same for all 4 terms)
        tot = fmin(fmax(tot, 1e-10), 1.0);
        out[0] = (float)tot;
    }
}

extern "C" void kernel_launch(void* const* d_in, const int* in_sizes, int n_in,
                              void* d_out, int out_size, void* d_ws, size_t ws_size,
                              hipStream_t stream) {
    const float* fnow  = (const float*)d_in[0];
    const float* fnext = (const float*)d_in[1];
    double* part = (double*)d_ws;          // 1024 doubles = 8 KiB scratch
    float*  out  = (float*)d_out;

    const int nblk = (NN / BAND) * 8;      // 1024 blocks
    physics_residual_kernel<<<dim3(nblk), 256, 0, stream>>>(fnow, fnext, part);
    final_reduce_kernel<<<1, 1024, 0, stream>>>(part, nblk, out);
}